// Round 1
// baseline (53.183 us; speedup 1.0000x reference)
//
#include <hip/hip_runtime.h>
#include <math.h>

#define NCITY 384
#define BATCH 4
#define DIM   128
#define HID   256
#define TR    6     // rows per encoder block -> 1536/6 = 256 blocks

// ---------------------------------------------------------------------------
// Kernel A: fused city-encoder + attention score + pairwise projections.
// One block handles TR=6 rows (cities). 256 threads.
//   h1  = relu(c @ We1 + be1)            [TR,256]  (LDS)
//   emb = h1 @ We2 + be2                 [TR,128]  (LDS)
//   score = relu(emb@Wa1+ba1) @ wa2 + ba2  (ws)
//   Ai  = emb @ Wd1[:D] + bd1            (ws)   (bd1 folded here)
//   Aj  = emb @ Wd1[D:]                  (ws)
// ---------------------------------------------------------------------------
__global__ __launch_bounds__(256) void encoder_kernel(
    const float* __restrict__ cities,
    const float* __restrict__ We1, const float* __restrict__ be1,
    const float* __restrict__ We2, const float* __restrict__ be2,
    const float* __restrict__ Wa1, const float* __restrict__ ba1,
    const float* __restrict__ wa2, const float* __restrict__ ba2,
    const float* __restrict__ Wd1, const float* __restrict__ bd1,
    float* __restrict__ score, float* __restrict__ Ai, float* __restrict__ Aj)
{
    __shared__ float h1_s[TR][HID];
    __shared__ float emb_s[TR][DIM];
    __shared__ float red_s[4][TR];
    __shared__ float c_s[TR][2];

    const int tid = threadIdx.x;
    const int r0  = blockIdx.x * TR;

    if (tid < TR * 2) ((float*)c_s)[tid] = cities[r0 * 2 + tid];
    __syncthreads();

    // h1 = relu(cities @ We1 + be1); thread owns h = tid
    {
        const float w0 = We1[tid], w1 = We1[HID + tid], b = be1[tid];
        #pragma unroll
        for (int rr = 0; rr < TR; ++rr)
            h1_s[rr][tid] = fmaxf(fmaf(c_s[rr][0], w0, fmaf(c_s[rr][1], w1, b)), 0.f);
    }
    __syncthreads();

    // emb = h1 @ We2 + be2; thread owns (d = tid&127), group g owns 3 rows
    {
        const int d = tid & (DIM - 1);
        const int g = tid >> 7;      // 0 or 1
        float a0 = 0.f, a1 = 0.f, a2 = 0.f;
        #pragma unroll 4
        for (int h = 0; h < HID; ++h) {
            const float w = We2[h * DIM + d];
            a0 = fmaf(h1_s[3 * g + 0][h], w, a0);
            a1 = fmaf(h1_s[3 * g + 1][h], w, a1);
            a2 = fmaf(h1_s[3 * g + 2][h], w, a2);
        }
        const float b = be2[d];
        emb_s[3 * g + 0][d] = a0 + b;
        emb_s[3 * g + 1][d] = a1 + b;
        emb_s[3 * g + 2][d] = a2 + b;
    }
    __syncthreads();

    // att hidden + Ai + Aj; thread owns h = tid
    float aa[TR], ai[TR], aj[TR];
    #pragma unroll
    for (int rr = 0; rr < TR; ++rr) { aa[rr] = 0.f; ai[rr] = 0.f; aj[rr] = 0.f; }

    #pragma unroll 4
    for (int d = 0; d < DIM; ++d) {
        const float wa = Wa1[d * HID + tid];
        const float wi = Wd1[d * HID + tid];
        const float wj = Wd1[(DIM + d) * HID + tid];
        #pragma unroll
        for (int rr = 0; rr < TR; ++rr) {
            const float e = emb_s[rr][d];
            aa[rr] = fmaf(e, wa, aa[rr]);
            ai[rr] = fmaf(e, wi, ai[rr]);
            aj[rr] = fmaf(e, wj, aj[rr]);
        }
    }

    const float ba1v = ba1[tid], wa2v = wa2[tid], bd1v = bd1[tid];
    #pragma unroll
    for (int rr = 0; rr < TR; ++rr) {
        float av = fmaxf(aa[rr] + ba1v, 0.f) * wa2v;
        #pragma unroll
        for (int off = 32; off > 0; off >>= 1)
            av += __shfl_down(av, off);
        if ((tid & 63) == 0) red_s[tid >> 6][rr] = av;
        Ai[(r0 + rr) * HID + tid] = ai[rr] + bd1v;
        Aj[(r0 + rr) * HID + tid] = aj[rr];
    }
    __syncthreads();
    if (tid < TR)
        score[r0 + tid] = red_s[0][tid] + red_s[1][tid] + red_s[2][tid]
                        + red_s[3][tid] + ba2[0];
}

// ---------------------------------------------------------------------------
// Kernel B: softmax over N=384 cities per batch. One block per batch.
// ---------------------------------------------------------------------------
__global__ __launch_bounds__(NCITY) void softmax_kernel(
    const float* __restrict__ score, float* __restrict__ att)
{
    __shared__ float red[8];
    const int b = blockIdx.x, t = threadIdx.x;
    const float v = score[b * NCITY + t];

    float m = v;
    #pragma unroll
    for (int off = 32; off > 0; off >>= 1)
        m = fmaxf(m, __shfl_down(m, off));
    if ((t & 63) == 0) red[t >> 6] = m;
    __syncthreads();
    m = red[0];
    #pragma unroll
    for (int w = 1; w < NCITY / 64; ++w) m = fmaxf(m, red[w]);

    const float e = __expf(v - m);
    float s = e;
    #pragma unroll
    for (int off = 32; off > 0; off >>= 1)
        s += __shfl_down(s, off);
    __syncthreads();
    if ((t & 63) == 0) red[t >> 6] = s;
    __syncthreads();
    s = 0.f;
    #pragma unroll
    for (int w = 0; w < NCITY / 64; ++w) s += red[w];

    att[b * NCITY + t] = e / s;
}

// ---------------------------------------------------------------------------
// Kernel C: pairwise decoder.
//   p[b,i,j] = sigmoid( sum_h relu(Ai[b,i,h] + Aj[b,j,h]) * wd2[h] + bd2 )
//   diagonal forced to 0.
// 32x32 (i,j) tile per block, 256 threads, 2x2 outputs/thread.
// LDS: two 32x256 f32 tiles = 64 KB, XOR-swizzled in float4 units so the
// stride-1KB row reads don't bank-conflict (Ai: conflict-free, Aj: 2-way=free).
// wd2 read via wave-uniform global loads (scalar cache).
// ---------------------------------------------------------------------------
__global__ __launch_bounds__(256) void pair_kernel(
    const float* __restrict__ Ai, const float* __restrict__ Aj,
    const float* __restrict__ wd2, const float* __restrict__ bd2,
    float* __restrict__ p)
{
    __shared__ float ai_s[32 * HID];
    __shared__ float aj_s[32 * HID];

    const int tid = threadIdx.x;
    const int b  = blockIdx.z;
    const int i0 = blockIdx.y * 32;
    const int j0 = blockIdx.x * 32;

    // stage 32 rows x 256 f32 of each array; swizzle c4' = c4 ^ (r&7)
    for (int t = tid; t < 32 * (HID / 4); t += 256) {
        const int r  = t >> 6;
        const int c4 = t & 63;
        const int cs = (c4 ^ (r & 7)) << 2;
        *(float4*)&ai_s[r * HID + cs] =
            *(const float4*)&Ai[(b * NCITY + i0 + r) * HID + (c4 << 2)];
        *(float4*)&aj_s[r * HID + cs] =
            *(const float4*)&Aj[(b * NCITY + j0 + r) * HID + (c4 << 2)];
    }
    __syncthreads();

    const int tx = tid & 15;        // j within tile (plus +16)
    const int ty = tid >> 4;        // i within tile (plus +16)
    const int sxi = ty & 7;         // swizzle key, same for ty and ty+16
    const int sxj = tx & 7;

    float acc00 = 0.f, acc01 = 0.f, acc10 = 0.f, acc11 = 0.f;

    #pragma unroll 4
    for (int k4 = 0; k4 < HID / 4; ++k4) {
        const int k  = k4 << 2;
        const int ci = (k4 ^ sxi) << 2;
        const int cj = (k4 ^ sxj) << 2;
        const float4 w  = *(const float4*)&wd2[k];              // uniform -> s_load
        const float4 x0 = *(const float4*)&ai_s[ ty       * HID + ci];
        const float4 x1 = *(const float4*)&ai_s[(ty + 16) * HID + ci];
        const float4 y0 = *(const float4*)&aj_s[ tx       * HID + cj];
        const float4 y1 = *(const float4*)&aj_s[(tx + 16) * HID + cj];

#define PK(ACC, X, Y)                                                  \
        ACC = fmaf(fmaxf(X.x + Y.x, 0.f), w.x, ACC);                   \
        ACC = fmaf(fmaxf(X.y + Y.y, 0.f), w.y, ACC);                   \
        ACC = fmaf(fmaxf(X.z + Y.z, 0.f), w.z, ACC);                   \
        ACC = fmaf(fmaxf(X.w + Y.w, 0.f), w.w, ACC);
        PK(acc00, x0, y0)
        PK(acc01, x0, y1)
        PK(acc10, x1, y0)
        PK(acc11, x1, y1)
#undef PK
    }

    const float bd = bd2[0];
    float accs[2][2] = {{acc00, acc01}, {acc10, acc11}};
    #pragma unroll
    for (int ii = 0; ii < 2; ++ii) {
        #pragma unroll
        for (int jj = 0; jj < 2; ++jj) {
            const int gi = i0 + ty + ii * 16;
            const int gj = j0 + tx + jj * 16;
            const float v = 1.f / (1.f + __expf(-(accs[ii][jj] + bd)));
            p[(b * NCITY + gi) * NCITY + gj] = (gi == gj) ? 0.f : v;
        }
    }
}

// ---------------------------------------------------------------------------
extern "C" void kernel_launch(void* const* d_in, const int* in_sizes, int n_in,
                              void* d_out, int out_size, void* d_ws, size_t ws_size,
                              hipStream_t stream)
{
    const float* cities = (const float*)d_in[0];
    const float* We1    = (const float*)d_in[1];
    const float* be1    = (const float*)d_in[2];
    const float* We2    = (const float*)d_in[3];
    const float* be2    = (const float*)d_in[4];
    const float* Wa1    = (const float*)d_in[5];
    const float* ba1    = (const float*)d_in[6];
    const float* wa2    = (const float*)d_in[7];
    const float* ba2    = (const float*)d_in[8];
    const float* Wd1    = (const float*)d_in[9];
    const float* bd1    = (const float*)d_in[10];
    const float* wd2    = (const float*)d_in[11];
    const float* bd2    = (const float*)d_in[12];

    float* out_att = (float*)d_out;                 // [4,384]
    float* out_p   = out_att + BATCH * NCITY;       // [4,384,384]

    float* score = (float*)d_ws;                    // 1536
    float* Ai    = score + BATCH * NCITY;           // 1536*256
    float* Aj    = Ai + BATCH * NCITY * HID;        // 1536*256

    encoder_kernel<<<(BATCH * NCITY) / TR, 256, 0, stream>>>(
        cities, We1, be1, We2, be2, Wa1, ba1, wa2, ba2, Wd1, bd1,
        score, Ai, Aj);

    softmax_kernel<<<BATCH, NCITY, 0, stream>>>(score, out_att);

    pair_kernel<<<dim3(NCITY / 32, NCITY / 32, BATCH), 256, 0, stream>>>(
        Ai, Aj, wd2, bd2, out_p);
}

// Round 2
// 46.245 us; speedup vs baseline: 1.1500x; 1.1500x over previous
//
#include <hip/hip_runtime.h>
#include <math.h>

#define NCITY 384
#define BATCH 4
#define DIM   128
#define HID   256
#define TR    6            // rows per encoder block -> 1536/6 = 256 blocks

#define CHUNK_FLOATS 32768 // 128 KB weight chunk

// ---------------------------------------------------------------------------
// Bulk global->LDS stage of one 128KB chunk via global_load_lds width=16.
// Layout is linear; each wave owns 1KB slots (i*4+wave), HW adds lane*16.
// ---------------------------------------------------------------------------
__device__ __forceinline__ void stage128(const float* __restrict__ gsrc,
                                         float* lbuf, int tid)
{
    const int lane = tid & 63;
    const int wv   = tid >> 6;
    #pragma unroll
    for (int i = 0; i < 32; ++i) {
        const int slot = i * 4 + wv;              // 0..127, 1KB each
        __builtin_amdgcn_global_load_lds(
            (const __attribute__((address_space(1))) void*)(gsrc + slot * 256 + lane * 4),
            (__attribute__((address_space(3))) void*)(lbuf + slot * 256),
            16, 0, 0);
    }
}

// ---------------------------------------------------------------------------
// GEMM of one staged chunk W[128][256] against emb_s[TR][128]:
//   out6[rr] = sum_k emb_s[rr][k] * W[k][tid]     (h = tid owns one column)
// Mapping: c4 = tid&63 (4 cols), wv = tid>>6 (k-split 4, 32 k each).
// Partials are reduced through the (now-dead) wbuf region.
// ---------------------------------------------------------------------------
__device__ __forceinline__ void chunk_gemm(float* wbuf,
                                           const float (*emb_s)[DIM],
                                           int tid, float out6[TR])
{
    const int c4 = tid & 63;
    const int wv = tid >> 6;
    const int k0 = wv * 32;

    float4 acc[TR];
    #pragma unroll
    for (int rr = 0; rr < TR; ++rr) { acc[rr].x = 0.f; acc[rr].y = 0.f; acc[rr].z = 0.f; acc[rr].w = 0.f; }

    #pragma unroll 2
    for (int kb = 0; kb < 32; kb += 4) {
        float4 ev[TR];
        #pragma unroll
        for (int rr = 0; rr < TR; ++rr)
            ev[rr] = *(const float4*)&emb_s[rr][k0 + kb];
        #pragma unroll
        for (int kk = 0; kk < 4; ++kk) {
            const float4 w4 = *(const float4*)&wbuf[(k0 + kb + kk) * HID + c4 * 4];
            #pragma unroll
            for (int rr = 0; rr < TR; ++rr) {
                const float e = ((const float*)&ev[rr])[kk];
                acc[rr].x = fmaf(e, w4.x, acc[rr].x);
                acc[rr].y = fmaf(e, w4.y, acc[rr].y);
                acc[rr].z = fmaf(e, w4.z, acc[rr].z);
                acc[rr].w = fmaf(e, w4.w, acc[rr].w);
            }
        }
    }
    __syncthreads();                       // all W reads done before overwrite
    #pragma unroll
    for (int rr = 0; rr < TR; ++rr)
        *(float4*)&wbuf[(wv * TR + rr) * HID + c4 * 4] = acc[rr];
    __syncthreads();
    #pragma unroll
    for (int rr = 0; rr < TR; ++rr)
        out6[rr] = wbuf[(0 * TR + rr) * HID + tid] + wbuf[(1 * TR + rr) * HID + tid]
                 + wbuf[(2 * TR + rr) * HID + tid] + wbuf[(3 * TR + rr) * HID + tid];
}

// ---------------------------------------------------------------------------
// Kernel A: fused encoder. 256 blocks x 256 threads, TR=6 rows each.
// Weights streamed chunk-wise (128KB) into LDS, compute from LDS.
// ---------------------------------------------------------------------------
__global__ __launch_bounds__(256) void encoder_kernel(
    const float* __restrict__ cities,
    const float* __restrict__ We1, const float* __restrict__ be1,
    const float* __restrict__ We2, const float* __restrict__ be2,
    const float* __restrict__ Wa1, const float* __restrict__ ba1,
    const float* __restrict__ wa2, const float* __restrict__ ba2,
    const float* __restrict__ Wd1, const float* __restrict__ bd1,
    float* __restrict__ score, float* __restrict__ Ai, float* __restrict__ Aj)
{
    __shared__ float wbuf[CHUNK_FLOATS];     // 128 KB
    __shared__ float h1_s[TR][HID];          // 6 KB
    __shared__ float emb_s[TR][DIM];         // 3 KB
    __shared__ float red2[4][TR];

    const int tid = threadIdx.x;
    const int r0  = blockIdx.x * TR;

    // issue We2 staging first; h1 compute overlaps the DMA
    stage128(We2, wbuf, tid);

    // h1 = relu(cities @ We1 + be1); thread owns h = tid (per-thread broadcast
    // loads of its rows' 12 city floats -> no pre-barrier needed)
    {
        const float w0 = We1[tid], w1 = We1[HID + tid], b = be1[tid];
        #pragma unroll
        for (int rr = 0; rr < TR; ++rr) {
            const float cx = cities[(r0 + rr) * 2];
            const float cy = cities[(r0 + rr) * 2 + 1];
            h1_s[rr][tid] = fmaxf(fmaf(cx, w0, fmaf(cy, w1, b)), 0.f);
        }
    }
    __syncthreads();    // drains We2 DMA (vmcnt 0) + h1 visible

    // ---- emb = h1 @ We2 + be2 ----------------------------------------------
    {
        const int d4 = tid & 31;      // 4 output cols: 4*d4
        const int ks = tid >> 5;      // k-split 8 (32 k each)
        const int k0 = ks * 32;
        float4 acc[TR];
        #pragma unroll
        for (int rr = 0; rr < TR; ++rr) { acc[rr].x = 0.f; acc[rr].y = 0.f; acc[rr].z = 0.f; acc[rr].w = 0.f; }

        #pragma unroll 2
        for (int kb = 0; kb < 32; kb += 4) {
            float4 hv[TR];
            #pragma unroll
            for (int rr = 0; rr < TR; ++rr)
                hv[rr] = *(const float4*)&h1_s[rr][k0 + kb];
            #pragma unroll
            for (int kk = 0; kk < 4; ++kk) {
                const float4 w4 = *(const float4*)&wbuf[(k0 + kb + kk) * DIM + d4 * 4];
                #pragma unroll
                for (int rr = 0; rr < TR; ++rr) {
                    const float h = ((const float*)&hv[rr])[kk];
                    acc[rr].x = fmaf(h, w4.x, acc[rr].x);
                    acc[rr].y = fmaf(h, w4.y, acc[rr].y);
                    acc[rr].z = fmaf(h, w4.z, acc[rr].z);
                    acc[rr].w = fmaf(h, w4.w, acc[rr].w);
                }
            }
        }
        // fold k-split pairs (lanes +-32 hold ks and ks^1)
        #pragma unroll
        for (int rr = 0; rr < TR; ++rr) {
            acc[rr].x += __shfl_xor(acc[rr].x, 32);
            acc[rr].y += __shfl_xor(acc[rr].y, 32);
            acc[rr].z += __shfl_xor(acc[rr].z, 32);
            acc[rr].w += __shfl_xor(acc[rr].w, 32);
        }
        __syncthreads();              // all We2 reads done -> wbuf reusable
        if ((tid & 63) < 32) {
            const int wv = tid >> 6;
            #pragma unroll
            for (int rr = 0; rr < TR; ++rr)
                *(float4*)&wbuf[(wv * TR + rr) * DIM + d4 * 4] = acc[rr];
        }
        __syncthreads();
        for (int o = tid; o < TR * DIM; o += 256) {
            const int rr = o >> 7, d = o & (DIM - 1);
            emb_s[rr][d] = wbuf[(0 * TR + rr) * DIM + d] + wbuf[(1 * TR + rr) * DIM + d]
                         + wbuf[(2 * TR + rr) * DIM + d] + wbuf[(3 * TR + rr) * DIM + d]
                         + be2[d];
        }
        __syncthreads();
    }

    // ---- chunk 1: Wa1 -> attention scores ----------------------------------
    stage128(Wa1, wbuf, tid);
    __syncthreads();
    {
        float o6[TR];
        chunk_gemm(wbuf, emb_s, tid, o6);
        const float ba1v = ba1[tid], wa2v = wa2[tid];
        const int wv = tid >> 6;
        #pragma unroll
        for (int rr = 0; rr < TR; ++rr) {
            float v = fmaxf(o6[rr] + ba1v, 0.f) * wa2v;
            #pragma unroll
            for (int off = 32; off > 0; off >>= 1)
                v += __shfl_down(v, off);
            if ((tid & 63) == 0) red2[wv][rr] = v;
        }
        __syncthreads();
        if (tid < TR)
            score[r0 + tid] = red2[0][tid] + red2[1][tid] + red2[2][tid] + red2[3][tid];
        // ba2 dropped: softmax is shift-invariant
    }

    // ---- chunk 2: Wd1 rows 0..127 -> Ai ------------------------------------
    stage128(Wd1, wbuf, tid);
    __syncthreads();
    {
        float o6[TR];
        chunk_gemm(wbuf, emb_s, tid, o6);
        const float bd1v = bd1[tid];
        #pragma unroll
        for (int rr = 0; rr < TR; ++rr)
            Ai[(r0 + rr) * HID + tid] = o6[rr] + bd1v;
        __syncthreads();              // protect wbuf until all reads done
    }

    // ---- chunk 3: Wd1 rows 128..255 -> Aj ----------------------------------
    stage128(Wd1 + DIM * HID, wbuf, tid);
    __syncthreads();
    {
        float o6[TR];
        chunk_gemm(wbuf, emb_s, tid, o6);
        #pragma unroll
        for (int rr = 0; rr < TR; ++rr)
            Aj[(r0 + rr) * HID + tid] = o6[rr];
    }
}

// ---------------------------------------------------------------------------
// Kernel B: softmax over N=384 cities per batch. One block per batch.
// ---------------------------------------------------------------------------
__global__ __launch_bounds__(NCITY) void softmax_kernel(
    const float* __restrict__ score, float* __restrict__ att)
{
    __shared__ float red[8];
    const int b = blockIdx.x, t = threadIdx.x;
    const float v = score[b * NCITY + t];

    float m = v;
    #pragma unroll
    for (int off = 32; off > 0; off >>= 1)
        m = fmaxf(m, __shfl_down(m, off));
    if ((t & 63) == 0) red[t >> 6] = m;
    __syncthreads();
    m = red[0];
    #pragma unroll
    for (int w = 1; w < NCITY / 64; ++w) m = fmaxf(m, red[w]);

    const float e = __expf(v - m);
    float s = e;
    #pragma unroll
    for (int off = 32; off > 0; off >>= 1)
        s += __shfl_down(s, off);
    __syncthreads();
    if ((t & 63) == 0) red[t >> 6] = s;
    __syncthreads();
    s = 0.f;
    #pragma unroll
    for (int w = 0; w < NCITY / 64; ++w) s += red[w];

    att[b * NCITY + t] = e / s;
}

// ---------------------------------------------------------------------------
// Kernel C: pairwise decoder (unchanged from R1 — correct, ~VALU-bound).
// ---------------------------------------------------------------------------
__global__ __launch_bounds__(256) void pair_kernel(
    const float* __restrict__ Ai, const float* __restrict__ Aj,
    const float* __restrict__ wd2, const float* __restrict__ bd2,
    float* __restrict__ p)
{
    __shared__ float ai_s[32 * HID];
    __shared__ float aj_s[32 * HID];

    const int tid = threadIdx.x;
    const int b  = blockIdx.z;
    const int i0 = blockIdx.y * 32;
    const int j0 = blockIdx.x * 32;

    for (int t = tid; t < 32 * (HID / 4); t += 256) {
        const int r  = t >> 6;
        const int c4 = t & 63;
        const int cs = (c4 ^ (r & 7)) << 2;
        *(float4*)&ai_s[r * HID + cs] =
            *(const float4*)&Ai[(b * NCITY + i0 + r) * HID + (c4 << 2)];
        *(float4*)&aj_s[r * HID + cs] =
            *(const float4*)&Aj[(b * NCITY + j0 + r) * HID + (c4 << 2)];
    }
    __syncthreads();

    const int tx = tid & 15;
    const int ty = tid >> 4;
    const int sxi = ty & 7;
    const int sxj = tx & 7;

    float acc00 = 0.f, acc01 = 0.f, acc10 = 0.f, acc11 = 0.f;

    #pragma unroll 4
    for (int k4 = 0; k4 < HID / 4; ++k4) {
        const int k  = k4 << 2;
        const int ci = (k4 ^ sxi) << 2;
        const int cj = (k4 ^ sxj) << 2;
        const float4 w  = *(const float4*)&wd2[k];
        const float4 x0 = *(const float4*)&ai_s[ ty       * HID + ci];
        const float4 x1 = *(const float4*)&ai_s[(ty + 16) * HID + ci];
        const float4 y0 = *(const float4*)&aj_s[ tx       * HID + cj];
        const float4 y1 = *(const float4*)&aj_s[(tx + 16) * HID + cj];

#define PK(ACC, X, Y)                                                  \
        ACC = fmaf(fmaxf(X.x + Y.x, 0.f), w.x, ACC);                   \
        ACC = fmaf(fmaxf(X.y + Y.y, 0.f), w.y, ACC);                   \
        ACC = fmaf(fmaxf(X.z + Y.z, 0.f), w.z, ACC);                   \
        ACC = fmaf(fmaxf(X.w + Y.w, 0.f), w.w, ACC);
        PK(acc00, x0, y0)
        PK(acc01, x0, y1)
        PK(acc10, x1, y0)
        PK(acc11, x1, y1)
#undef PK
    }

    const float bd = bd2[0];
    float accs[2][2] = {{acc00, acc01}, {acc10, acc11}};
    #pragma unroll
    for (int ii = 0; ii < 2; ++ii) {
        #pragma unroll
        for (int jj = 0; jj < 2; ++jj) {
            const int gi = i0 + ty + ii * 16;
            const int gj = j0 + tx + jj * 16;
            const float v = 1.f / (1.f + __expf(-(accs[ii][jj] + bd)));
            p[(b * NCITY + gi) * NCITY + gj] = (gi == gj) ? 0.f : v;
        }
    }
}

// ---------------------------------------------------------------------------
extern "C" void kernel_launch(void* const* d_in, const int* in_sizes, int n_in,
                              void* d_out, int out_size, void* d_ws, size_t ws_size,
                              hipStream_t stream)
{
    const float* cities = (const float*)d_in[0];
    const float* We1    = (const float*)d_in[1];
    const float* be1    = (const float*)d_in[2];
    const float* We2    = (const float*)d_in[3];
    const float* be2    = (const float*)d_in[4];
    const float* Wa1    = (const float*)d_in[5];
    const float* ba1    = (const float*)d_in[6];
    const float* wa2    = (const float*)d_in[7];
    const float* ba2    = (const float*)d_in[8];
    const float* Wd1    = (const float*)d_in[9];
    const float* bd1    = (const float*)d_in[10];
    const float* wd2    = (const float*)d_in[11];
    const float* bd2    = (const float*)d_in[12];
    (void)ba2;

    float* out_att = (float*)d_out;                 // [4,384]
    float* out_p   = out_att + BATCH * NCITY;       // [4,384,384]

    float* score = (float*)d_ws;                    // 1536
    float* Ai    = score + BATCH * NCITY;           // 1536*256
    float* Aj    = Ai + BATCH * NCITY * HID;        // 1536*256

    encoder_kernel<<<(BATCH * NCITY) / TR, 256, 0, stream>>>(
        cities, We1, be1, We2, be2, Wa1, ba1, wa2, ba2, Wd1, bd1,
        score, Ai, Aj);

    softmax_kernel<<<BATCH, NCITY, 0, stream>>>(score, out_att);

    pair_kernel<<<dim3(NCITY / 32, NCITY / 32, BATCH), 256, 0, stream>>>(
        Ai, Aj, wd2, bd2, out_p);
}